// Round 3
// baseline (173.147 us; speedup 1.0000x reference)
//
#include <hip/hip_runtime.h>
#include <hip/hip_bf16.h>
#include <hip/hip_cooperative_groups.h>

namespace cg = cooperative_groups;

#define NN 512
#define DD 512
#define MARGIN_F 1.0f

constexpr int BM = 64, BN = 64, BK = 32, KSPLIT = 4, KCH = DD / KSPLIT;

// One cooperative kernel, 256 blocks x 256 threads (1 block/CU).
// Phase A: partial grams part[z] = E_z E_z^T (64 tiles x KSPLIT=4 = 256 blocks)
// Phase B: per-anchor triplet sums (2 anchors per block)
// Phase C: block 0 final reduction
__global__ __launch_bounds__(256) void k_fused(const float* __restrict__ E,
                                               const int* __restrict__ labels,
                                               float* __restrict__ part,
                                               float* __restrict__ diag,
                                               float* __restrict__ s_part,
                                               int* __restrict__ np_part,
                                               float* __restrict__ out) {
    cg::grid_group grid = cg::this_grid();

    __shared__ float As[BK][BM + 4];  // 8.5 KB, k-major, +4 pad
    __shared__ float Bs[BK][BN + 4];  // 8.5 KB
    __shared__ int nPosSh;
    __shared__ float wsum[4];
    __shared__ double ws_[4];
    __shared__ long long wc_[4];
    float* posv = &As[0][0];  // phase-B alias: needs 512 floats, As holds 2176

    const int tid = threadIdx.x;
    const int bid = blockIdx.x;

    // ---------------- phase A: gram tile ----------------
    {
        const int tileId = bid & 63;   // 8x8 tiles of 64x64
        const int z = bid >> 6;        // K chunk 0..3
        const int row0 = (tileId >> 3) * BM;
        const int col0 = (tileId & 7) * BN;
        const int k0 = z * KCH;
        const int tx = tid & 15, ty = tid >> 4;
        float acc[4][4] = {};
        for (int kt = 0; kt < KCH; kt += BK) {
#pragma unroll
            for (int q = 0; q < 2; ++q) {
                int idx = tid + q * 256;  // 0..511
                int r = idx >> 3;         // 0..63
                int kv = idx & 7;         // float4 within 32-wide K tile
                float4 va = *reinterpret_cast<const float4*>(
                    &E[(size_t)(row0 + r) * DD + k0 + kt + kv * 4]);
                As[kv * 4 + 0][r] = va.x;
                As[kv * 4 + 1][r] = va.y;
                As[kv * 4 + 2][r] = va.z;
                As[kv * 4 + 3][r] = va.w;
                float4 vb = *reinterpret_cast<const float4*>(
                    &E[(size_t)(col0 + r) * DD + k0 + kt + kv * 4]);
                Bs[kv * 4 + 0][r] = vb.x;
                Bs[kv * 4 + 1][r] = vb.y;
                Bs[kv * 4 + 2][r] = vb.z;
                Bs[kv * 4 + 3][r] = vb.w;
            }
            __syncthreads();
#pragma unroll
            for (int k = 0; k < BK; ++k) {
                float4 av = *reinterpret_cast<const float4*>(&As[k][ty * 4]);
                float4 bv = *reinterpret_cast<const float4*>(&Bs[k][tx * 4]);
                float a[4] = {av.x, av.y, av.z, av.w};
                float b[4] = {bv.x, bv.y, bv.z, bv.w};
#pragma unroll
                for (int i = 0; i < 4; ++i)
#pragma unroll
                    for (int j = 0; j < 4; ++j) acc[i][j] += a[i] * b[j];
            }
            __syncthreads();
        }
        float* pz = part + (size_t)z * NN * NN;
#pragma unroll
        for (int i = 0; i < 4; ++i) {
            int gi = row0 + ty * 4 + i;
            float4 st = make_float4(acc[i][0], acc[i][1], acc[i][2], acc[i][3]);
            *reinterpret_cast<float4*>(&pz[(size_t)gi * NN + col0 + tx * 4]) = st;
        }
        if (row0 == col0 && tx == ty) {
#pragma unroll
            for (int i = 0; i < 4; ++i) diag[z * NN + row0 + ty * 4 + i] = acc[i][i];
        }
    }

    __threadfence();
    grid.sync();

    // ---------------- phase B: 2 anchors per block ----------------
    for (int s = 0; s < 2; ++s) {
        const int a = (bid << 1) + s;
        if (tid == 0) nPosSh = 0;
        __syncthreads();  // also orders posv reuse across iterations
        const int la = labels[a];
        const float g_aa =
            diag[a] + diag[NN + a] + diag[2 * NN + a] + diag[3 * NN + a];
        float dval[2];
        int neg[2];
#pragma unroll
        for (int q = 0; q < 2; ++q) {
            int j = tid + q * 256;
            float g_aj = part[(size_t)0 * NN * NN + (size_t)a * NN + j] +
                         part[(size_t)1 * NN * NN + (size_t)a * NN + j] +
                         part[(size_t)2 * NN * NN + (size_t)a * NN + j] +
                         part[(size_t)3 * NN * NN + (size_t)a * NN + j];
            float g_jj = diag[j] + diag[NN + j] + diag[2 * NN + j] + diag[3 * NN + j];
            float d = g_aa + g_jj - 2.0f * g_aj;
            dval[q] = d;
            neg[q] = 0;
            if (j != a) {
                if (labels[j] == la) {
                    int p = atomicAdd(&nPosSh, 1);  // LDS atomic, ~7 per anchor
                    posv[p] = d;
                } else {
                    neg[q] = 1;
                }
            }
        }
        __syncthreads();
        const int np = nPosSh;  // block-uniform
        float acc = 0.f;
#pragma unroll
        for (int q = 0; q < 2; ++q) {
            if (neg[q]) {
                float d = dval[q] - MARGIN_F;  // term = pos - dval + margin
                for (int p = 0; p < np; ++p) acc += fmaxf(posv[p] - d, 0.f);
            }
        }
#pragma unroll
        for (int off = 32; off > 0; off >>= 1) acc += __shfl_down(acc, off);
        if ((tid & 63) == 0) wsum[tid >> 6] = acc;
        __syncthreads();
        if (tid == 0) {
            s_part[a] = wsum[0] + wsum[1] + wsum[2] + wsum[3];
            np_part[a] = np;
        }
    }

    __threadfence();
    grid.sync();

    // ---------------- phase C: final reduction (block 0) ----------------
    if (bid == 0) {
        double sd = 0.0;
        long long c = 0;
        for (int i = tid; i < NN; i += 256) {
            sd += (double)s_part[i];
            int np = np_part[i];
            c += (long long)np * (511 - np);
        }
#pragma unroll
        for (int off = 32; off > 0; off >>= 1) {
            sd += __shfl_down(sd, off);
            c += __shfl_down(c, off);
        }
        if ((tid & 63) == 0) {
            ws_[tid >> 6] = sd;
            wc_[tid >> 6] = c;
        }
        __syncthreads();
        if (tid == 0) {
            double tot = ws_[0] + ws_[1] + ws_[2] + ws_[3];
            long long cnt = wc_[0] + wc_[1] + wc_[2] + wc_[3];
            if (cnt < 1) cnt = 1;
            out[0] = (float)(tot / (double)cnt);
        }
    }
}

extern "C" void kernel_launch(void* const* d_in, const int* in_sizes, int n_in,
                              void* d_out, int out_size, void* d_ws, size_t ws_size,
                              hipStream_t stream) {
    const float* E = (const float*)d_in[0];
    const int* labels = (const int*)d_in[1];
    float* out = (float*)d_out;

    // workspace layout (bytes)
    float* part = (float*)d_ws;  // 4 * 512*512*4 = 4 MiB
    float* diag = (float*)((char*)d_ws + (size_t)KSPLIT * NN * NN * 4);  // 8 KiB
    float* s_part = (float*)((char*)diag + (size_t)KSPLIT * NN * 4);     // 2 KiB
    int* np_part = (int*)((char*)s_part + (size_t)NN * 4);               // 2 KiB

    void* args[] = {(void*)&E,      (void*)&labels,  (void*)&part,
                    (void*)&diag,   (void*)&s_part,  (void*)&np_part,
                    (void*)&out};
    hipLaunchCooperativeKernel((void*)k_fused, dim3(256), dim3(256), args, 0,
                               stream);
}

// Round 4
// 142.198 us; speedup vs baseline: 1.2176x; 1.2176x over previous
//
#include <hip/hip_runtime.h>
#include <hip/hip_bf16.h>

#define NN 512
#define DD 512
#define MARGIN_F 1.0f
#define KT 64            // k-columns per staging round
#define NKT (DD / KT)    // 8 rounds per j-tile

// One block per 2 anchors (256 blocks x 256 threads, 1 block/CU).
// Each block streams all of E through LDS (L2-resident), computes
// d(a,j) = ||e_a - e_j||^2 for its 2 anchors and all 512 j, then does the
// compacted pos x neg triplet accumulation entirely in-block.
__global__ __launch_bounds__(256) void k_fused(const float* __restrict__ E,
                                               const int* __restrict__ labels,
                                               float* __restrict__ s_part,
                                               int* __restrict__ c_part) {
    __shared__ float tile[256][KT];  // 64 KB, XOR-swizzled float4 chunks
    __shared__ float ea[2][DD];      // 4 KB anchor rows
    __shared__ int lab[NN];          // 2 KB
    __shared__ float posv[2][64];    // compacted positive distances
    __shared__ int nP[2];
    __shared__ float wsum[4];

    const int tid = threadIdx.x;
    const int bid = blockIdx.x;
    const int a0 = bid * 2, a1 = a0 + 1;

    if (tid == 0) { nP[0] = 0; nP[1] = 0; }
    // preload anchor rows (1024 floats = 256 float4) + labels
    {
        int row = tid >> 7, c4 = (tid & 127) * 4;
        *(float4*)&ea[row][c4] = *(const float4*)&E[(size_t)(a0 + row) * DD + c4];
        lab[tid] = labels[tid];
        lab[tid + 256] = labels[tid + 256];
    }

    float4 ld[16];  // in-flight staging registers (T14 async-stage split)
    float dacc[2][2] = {{0.f, 0.f}, {0.f, 0.f}};  // [jtile][anchor]

    auto issue = [&](int jbase, int kt) {
#pragma unroll
        for (int p = 0; p < 16; ++p) {
            int idx = p * 256 + tid;
            int r = idx >> 4, kv = idx & 15;  // 16 rows x 64B segments: coalesced
            ld[p] = *(const float4*)&E[(size_t)(jbase + r) * DD + kt * KT + kv * 4];
        }
    };
    auto swrite = [&]() {
#pragma unroll
        for (int p = 0; p < 16; ++p) {
            int idx = p * 256 + tid;
            int r = idx >> 4, kv = idx & 15;
            *(float4*)&tile[r][(kv ^ (r & 7)) << 2] = ld[p];  // XOR swizzle
        }
    };

    issue(0, 0);  // prologue: first k-tile of j-tile 0

#pragma unroll
    for (int jt = 0; jt < 2; ++jt) {
#pragma unroll 1
        for (int kt = 0; kt < NKT; ++kt) {
            __syncthreads();  // previous round's compute done; tile free
            swrite();         // compiler inserts vmcnt wait on ld[]
            __syncthreads();
            // issue next round's loads: they fly during this round's compute
            if (jt == 0) {
                if (kt < NKT - 1) issue(0, kt + 1);
                else issue(256, 0);
            } else {
                if (kt < NKT - 1) issue(256, kt + 1);
            }
#pragma unroll
            for (int c = 0; c < 16; ++c) {
                float4 v = *(const float4*)&tile[tid][(c ^ (tid & 7)) << 2];
                float4 w0 = *(const float4*)&ea[0][kt * KT + (c << 2)];
                float4 w1 = *(const float4*)&ea[1][kt * KT + (c << 2)];
                float t;
                t = w0.x - v.x; dacc[jt][0] += t * t;
                t = w0.y - v.y; dacc[jt][0] += t * t;
                t = w0.z - v.z; dacc[jt][0] += t * t;
                t = w0.w - v.w; dacc[jt][0] += t * t;
                t = w1.x - v.x; dacc[jt][1] += t * t;
                t = w1.y - v.y; dacc[jt][1] += t * t;
                t = w1.z - v.z; dacc[jt][1] += t * t;
                t = w1.w - v.w; dacc[jt][1] += t * t;
            }
        }
    }

    // ---------------- in-block triplet phase ----------------
    const int la0 = lab[a0], la1 = lab[a1];
    const int j0 = tid, j1 = tid + 256;
    if (j0 != a0 && lab[j0] == la0) { int p = atomicAdd(&nP[0], 1); posv[0][p] = dacc[0][0]; }
    if (j0 != a1 && lab[j0] == la1) { int p = atomicAdd(&nP[1], 1); posv[1][p] = dacc[0][1]; }
    if (j1 != a0 && lab[j1] == la0) { int p = atomicAdd(&nP[0], 1); posv[0][p] = dacc[1][0]; }
    if (j1 != a1 && lab[j1] == la1) { int p = atomicAdd(&nP[1], 1); posv[1][p] = dacc[1][1]; }
    __syncthreads();
    const int np0 = nP[0], np1 = nP[1];
    float acc = 0.f;
    if (lab[j0] != la0) { float b = MARGIN_F - dacc[0][0]; for (int p = 0; p < np0; ++p) acc += fmaxf(posv[0][p] + b, 0.f); }
    if (lab[j0] != la1) { float b = MARGIN_F - dacc[0][1]; for (int p = 0; p < np1; ++p) acc += fmaxf(posv[1][p] + b, 0.f); }
    if (lab[j1] != la0) { float b = MARGIN_F - dacc[1][0]; for (int p = 0; p < np0; ++p) acc += fmaxf(posv[0][p] + b, 0.f); }
    if (lab[j1] != la1) { float b = MARGIN_F - dacc[1][1]; for (int p = 0; p < np1; ++p) acc += fmaxf(posv[1][p] + b, 0.f); }

#pragma unroll
    for (int off = 32; off > 0; off >>= 1) acc += __shfl_down(acc, off);
    if ((tid & 63) == 0) wsum[tid >> 6] = acc;
    __syncthreads();
    if (tid == 0) {
        s_part[bid] = wsum[0] + wsum[1] + wsum[2] + wsum[3];
        c_part[bid] = np0 * (511 - np0) + np1 * (511 - np1);
    }
}

// ---------------- finalize: reduce 256 block partials ----------------
__global__ __launch_bounds__(256) void k_finalize(const float* __restrict__ s_part,
                                                  const int* __restrict__ c_part,
                                                  float* __restrict__ out) {
    const int tid = threadIdx.x;
    double s = (double)s_part[tid];
    long long c = (long long)c_part[tid];
#pragma unroll
    for (int off = 32; off > 0; off >>= 1) {
        s += __shfl_down(s, off);
        c += __shfl_down(c, off);
    }
    __shared__ double ws_[4];
    __shared__ long long wc_[4];
    if ((tid & 63) == 0) { ws_[tid >> 6] = s; wc_[tid >> 6] = c; }
    __syncthreads();
    if (tid == 0) {
        double tot = ws_[0] + ws_[1] + ws_[2] + ws_[3];
        long long cnt = wc_[0] + wc_[1] + wc_[2] + wc_[3];
        if (cnt < 1) cnt = 1;
        out[0] = (float)(tot / (double)cnt);
    }
}

extern "C" void kernel_launch(void* const* d_in, const int* in_sizes, int n_in,
                              void* d_out, int out_size, void* d_ws, size_t ws_size,
                              hipStream_t stream) {
    const float* E = (const float*)d_in[0];
    const int* labels = (const int*)d_in[1];
    float* out = (float*)d_out;

    float* s_part = (float*)d_ws;              // 256 floats
    int* c_part = (int*)((char*)d_ws + 2048);  // 256 ints

    k_fused<<<256, 256, 0, stream>>>(E, labels, s_part, c_part);
    k_finalize<<<1, 256, 0, stream>>>(s_part, c_part, out);
}

// Round 5
// 86.678 us; speedup vs baseline: 1.9976x; 1.6405x over previous
//
#include <hip/hip_runtime.h>
#include <hip/hip_bf16.h>

#define NN 512
#define DD 512
#define MARGIN_F 1.0f

constexpr int BM = 64, BN = 64, BK = 32, KSPLIT = 4, KCH = DD / KSPLIT;

// ---------------- kernel 1: partial grams part[z] = E_z E_z^T ------------
// Plain stores (no init needed, no atomics). Diagonal blocks also write
// diag[z][j] = part[z][j][j]. Block (0,0,0) zeroes the accumulators used
// by kernel 2 (visible at kernel boundary).
__global__ __launch_bounds__(256) void k_gram(const float* __restrict__ E,
                                              float* __restrict__ part,
                                              float* __restrict__ diag,
                                              double* __restrict__ g_sum,
                                              unsigned long long* __restrict__ g_cnt,
                                              unsigned int* __restrict__ done) {
    __shared__ float As[BK][BM + 4];  // k-major, +4 pad
    __shared__ float Bs[BK][BN + 4];
    const int tid = threadIdx.x;
    if (blockIdx.x == 0 && blockIdx.y == 0 && blockIdx.z == 0 && tid == 0) {
        *g_sum = 0.0;
        *g_cnt = 0ull;
        *done = 0u;
    }
    const int tx = tid & 15, ty = tid >> 4;
    const int row0 = blockIdx.y * BM, col0 = blockIdx.x * BN;
    const int z = blockIdx.z;
    const int k0 = z * KCH;
    float acc[4][4] = {};
    for (int kt = 0; kt < KCH; kt += BK) {
#pragma unroll
        for (int q = 0; q < 2; ++q) {
            int idx = tid + q * 256;  // 0..511
            int r = idx >> 3;         // 0..63
            int kv = idx & 7;         // float4 within the 32-wide K tile
            float4 va = *reinterpret_cast<const float4*>(
                &E[(size_t)(row0 + r) * DD + k0 + kt + kv * 4]);
            As[kv * 4 + 0][r] = va.x;
            As[kv * 4 + 1][r] = va.y;
            As[kv * 4 + 2][r] = va.z;
            As[kv * 4 + 3][r] = va.w;
            float4 vb = *reinterpret_cast<const float4*>(
                &E[(size_t)(col0 + r) * DD + k0 + kt + kv * 4]);
            Bs[kv * 4 + 0][r] = vb.x;
            Bs[kv * 4 + 1][r] = vb.y;
            Bs[kv * 4 + 2][r] = vb.z;
            Bs[kv * 4 + 3][r] = vb.w;
        }
        __syncthreads();
#pragma unroll
        for (int k = 0; k < BK; ++k) {
            float4 av = *reinterpret_cast<const float4*>(&As[k][ty * 4]);
            float4 bv = *reinterpret_cast<const float4*>(&Bs[k][tx * 4]);
            float a[4] = {av.x, av.y, av.z, av.w};
            float b[4] = {bv.x, bv.y, bv.z, bv.w};
#pragma unroll
            for (int i = 0; i < 4; ++i)
#pragma unroll
                for (int j = 0; j < 4; ++j) acc[i][j] += a[i] * b[j];
        }
        __syncthreads();
    }
    float* pz = part + (size_t)z * NN * NN;
#pragma unroll
    for (int i = 0; i < 4; ++i) {
        int gi = row0 + ty * 4 + i;
        float4 st = make_float4(acc[i][0], acc[i][1], acc[i][2], acc[i][3]);
        *reinterpret_cast<float4*>(&pz[(size_t)gi * NN + col0 + tx * 4]) = st;
    }
    if (row0 == col0 && tx == ty) {
#pragma unroll
        for (int i = 0; i < 4; ++i) diag[z * NN + row0 + ty * 4 + i] = acc[i][i];
    }
}

// ---------------- kernel 2: per-anchor triplet + fused finalize ----------
// dist(a,j) = g_aa + g_jj - 2*g_aj reconstructed from the 4 partials.
// Per-block result goes into device-scope atomics; the LAST block to
// finish computes out = sum / count (reads via atomic RMW for cross-XCD
// coherence).
__global__ __launch_bounds__(256) void k_triplet(const float* __restrict__ part,
                                                 const float* __restrict__ diag,
                                                 const int* __restrict__ labels,
                                                 double* __restrict__ g_sum,
                                                 unsigned long long* __restrict__ g_cnt,
                                                 unsigned int* __restrict__ done,
                                                 float* __restrict__ out) {
    const int a = blockIdx.x;
    const int tid = threadIdx.x;
    __shared__ float posv[NN];
    __shared__ int nPos;
    __shared__ float wsum[4];
    if (tid == 0) nPos = 0;
    __syncthreads();
    const int la = labels[a];
    const float g_aa =
        diag[a] + diag[NN + a] + diag[2 * NN + a] + diag[3 * NN + a];
    float dval[2];
    int neg[2];
#pragma unroll
    for (int q = 0; q < 2; ++q) {
        int j = tid + q * 256;
        float g_aj = part[(size_t)0 * NN * NN + (size_t)a * NN + j] +
                     part[(size_t)1 * NN * NN + (size_t)a * NN + j] +
                     part[(size_t)2 * NN * NN + (size_t)a * NN + j] +
                     part[(size_t)3 * NN * NN + (size_t)a * NN + j];
        float g_jj = diag[j] + diag[NN + j] + diag[2 * NN + j] + diag[3 * NN + j];
        float d = g_aa + g_jj - 2.0f * g_aj;
        dval[q] = d;
        neg[q] = 0;
        if (j != a) {
            if (labels[j] == la) {
                int p = atomicAdd(&nPos, 1);  // LDS atomic, ~7 per anchor
                posv[p] = d;
            } else {
                neg[q] = 1;
            }
        }
    }
    __syncthreads();
    const int np = nPos;  // block-uniform
    float acc = 0.f;
#pragma unroll
    for (int q = 0; q < 2; ++q) {
        if (neg[q]) {
            float b = MARGIN_F - dval[q];  // term = pos - dval + margin
            for (int p = 0; p < np; ++p) acc += fmaxf(posv[p] + b, 0.f);
        }
    }
#pragma unroll
    for (int off = 32; off > 0; off >>= 1) acc += __shfl_down(acc, off);
    if ((tid & 63) == 0) wsum[tid >> 6] = acc;
    __syncthreads();
    if (tid == 0) {
        double tot = (double)wsum[0] + (double)wsum[1] + (double)wsum[2] +
                     (double)wsum[3];
        atomicAdd(g_sum, tot);
        atomicAdd(g_cnt, (unsigned long long)((long long)np * (511 - np)));
        __threadfence();
        unsigned int prev = atomicAdd(done, 1u);
        if (prev == NN - 1) {  // last block finalizes
            double s = atomicAdd(g_sum, 0.0);            // coherent read
            unsigned long long c = atomicAdd(g_cnt, 0ull);  // coherent read
            if (c < 1ull) c = 1ull;
            out[0] = (float)(s / (double)c);
        }
    }
}

extern "C" void kernel_launch(void* const* d_in, const int* in_sizes, int n_in,
                              void* d_out, int out_size, void* d_ws, size_t ws_size,
                              hipStream_t stream) {
    const float* E = (const float*)d_in[0];
    const int* labels = (const int*)d_in[1];
    float* out = (float*)d_out;

    // workspace layout (bytes)
    float* part = (float*)d_ws;  // 4 * 512*512*4 = 4 MiB
    float* diag = (float*)((char*)d_ws + (size_t)KSPLIT * NN * NN * 4);  // 8 KiB
    double* g_sum = (double*)((char*)diag + (size_t)KSPLIT * NN * 4);
    unsigned long long* g_cnt = (unsigned long long*)(g_sum + 1);
    unsigned int* done = (unsigned int*)(g_cnt + 1);

    k_gram<<<dim3(NN / BN, NN / BM, KSPLIT), 256, 0, stream>>>(E, part, diag,
                                                               g_sum, g_cnt, done);
    k_triplet<<<NN, 256, 0, stream>>>(part, diag, labels, g_sum, g_cnt, done, out);
}

// Round 8
// 74.280 us; speedup vs baseline: 2.3310x; 1.1669x over previous
//
#include <hip/hip_runtime.h>
#include <hip/hip_bf16.h>

#define NN 512
#define DD 512
#define MARGIN_F 1.0f
#define BKD 64      // K step for dist kernel
#define NSTEP (DD / BKD)

// ---------------- kernel 1: direct distance tiles ------------------------
// Grid 16x16 (256 blocks, 1/CU), 256 threads. Each block computes the full
// 32x32 dist tile d(i,j) = sq_i + sq_j - 2*<e_i,e_j> with K=512 in-block:
// no split-K partials, no separate diag pass. Row norms are accumulated
// during staging and reduced via shfl over the 16 threads sharing a row.
__global__ __launch_bounds__(256) void k_dist(const float* __restrict__ E,
                                              float* __restrict__ dist) {
    __shared__ float As[BKD][34];  // k-major, +2 pad (8B-aligned float2 reads)
    __shared__ float Bs[BKD][34];
    __shared__ float sqA[32], sqB[32];

    const int tid = threadIdx.x;
    const int R = blockIdx.y * 32, C = blockIdx.x * 32;
    const int r0 = tid >> 4;  // 0..15 (also ty for compute)
    const int kv = tid & 15;  // float4 slot in 64-wide K (also tx for compute)

    float4 pa0, pa1, pb0, pb1;  // in-flight staging registers
    auto issue = [&](int kt) {
        const float* pA = E + (size_t)(R + r0) * DD + kt * BKD + kv * 4;
        pa0 = *(const float4*)pA;
        pa1 = *(const float4*)(pA + 16 * DD);
        const float* pB = E + (size_t)(C + r0) * DD + kt * BKD + kv * 4;
        pb0 = *(const float4*)pB;
        pb1 = *(const float4*)(pB + 16 * DD);
    };

    float sa0 = 0.f, sa1 = 0.f, sb0 = 0.f, sb1 = 0.f;  // row-norm partials
    float a00 = 0.f, a01 = 0.f, a10 = 0.f, a11 = 0.f;  // 2x2 micro-tile

    issue(0);
#pragma unroll 1
    for (int kt = 0; kt < NSTEP; ++kt) {
        // row-norm accumulation from the staged registers (first use -> vmcnt)
        sa0 += pa0.x * pa0.x + pa0.y * pa0.y + pa0.z * pa0.z + pa0.w * pa0.w;
        sa1 += pa1.x * pa1.x + pa1.y * pa1.y + pa1.z * pa1.z + pa1.w * pa1.w;
        sb0 += pb0.x * pb0.x + pb0.y * pb0.y + pb0.z * pb0.z + pb0.w * pb0.w;
        sb1 += pb1.x * pb1.x + pb1.y * pb1.y + pb1.z * pb1.z + pb1.w * pb1.w;
        __syncthreads();  // previous step's compute done; LDS free
        {
            const float fa0[4] = {pa0.x, pa0.y, pa0.z, pa0.w};
            const float fa1[4] = {pa1.x, pa1.y, pa1.z, pa1.w};
            const float fb0[4] = {pb0.x, pb0.y, pb0.z, pb0.w};
            const float fb1[4] = {pb1.x, pb1.y, pb1.z, pb1.w};
#pragma unroll
            for (int c = 0; c < 4; ++c) {
                As[kv * 4 + c][r0] = fa0[c];
                As[kv * 4 + c][r0 + 16] = fa1[c];
                Bs[kv * 4 + c][r0] = fb0[c];
                Bs[kv * 4 + c][r0 + 16] = fb1[c];
            }
        }
        __syncthreads();
        if (kt < NSTEP - 1) issue(kt + 1);  // loads fly under compute
#pragma unroll
        for (int k = 0; k < BKD; ++k) {
            float2 av = *(const float2*)&As[k][r0 * 2];  // broadcast (free)
            float2 bv = *(const float2*)&Bs[k][kv * 2];  // conflict-free
            a00 += av.x * bv.x;
            a01 += av.x * bv.y;
            a10 += av.y * bv.x;
            a11 += av.y * bv.y;
        }
    }

    // reduce row-norm partials across the 16 threads sharing each row
#pragma unroll
    for (int m = 1; m <= 8; m <<= 1) {
        sa0 += __shfl_xor(sa0, m);
        sa1 += __shfl_xor(sa1, m);
        sb0 += __shfl_xor(sb0, m);
        sb1 += __shfl_xor(sb1, m);
    }
    if (kv == 0) {
        sqA[r0] = sa0;
        sqA[r0 + 16] = sa1;
        sqB[r0] = sb0;
        sqB[r0 + 16] = sb1;
    }
    __syncthreads();

    const float qa0 = sqA[r0 * 2], qa1 = sqA[r0 * 2 + 1];
    const float qb0 = sqB[kv * 2], qb1 = sqB[kv * 2 + 1];
    float2 o0 = make_float2(qa0 + qb0 - 2.f * a00, qa0 + qb1 - 2.f * a01);
    float2 o1 = make_float2(qa1 + qb0 - 2.f * a10, qa1 + qb1 - 2.f * a11);
    *(float2*)&dist[(size_t)(R + r0 * 2) * NN + C + kv * 2] = o0;
    *(float2*)&dist[(size_t)(R + r0 * 2 + 1) * NN + C + kv * 2] = o1;
}

// ---------------- kernel 2: per-anchor triplet sums ----------------------
// Reads finished dist rows directly (1 float per j). Plain stores of
// per-anchor partials (distinct addresses — no contended atomics).
__global__ __launch_bounds__(256) void k_triplet(const float* __restrict__ dist,
                                                 const int* __restrict__ labels,
                                                 float* __restrict__ s_part,
                                                 int* __restrict__ np_part) {
    const int a = blockIdx.x;
    const int tid = threadIdx.x;
    __shared__ float posv[64];
    __shared__ int nPos;
    __shared__ float wsum[4];
    if (tid == 0) nPos = 0;
    __syncthreads();
    const int la = labels[a];
    float dval[2];
    int neg[2];
#pragma unroll
    for (int q = 0; q < 2; ++q) {
        int j = tid + q * 256;
        float d = dist[(size_t)a * NN + j];
        dval[q] = d;
        neg[q] = 0;
        if (j != a) {
            if (labels[j] == la) {
                int p = atomicAdd(&nPos, 1);  // LDS atomic, ~7 per anchor
                posv[p] = d;
            } else {
                neg[q] = 1;
            }
        }
    }
    __syncthreads();
    const int np = nPos;  // block-uniform
    float acc = 0.f;
#pragma unroll
    for (int q = 0; q < 2; ++q) {
        if (neg[q]) {
            float b = MARGIN_F - dval[q];  // term = pos - dval + margin
            for (int p = 0; p < np; ++p) acc += fmaxf(posv[p] + b, 0.f);
        }
    }
#pragma unroll
    for (int off = 32; off > 0; off >>= 1) acc += __shfl_down(acc, off);
    if ((tid & 63) == 0) wsum[tid >> 6] = acc;
    __syncthreads();
    if (tid == 0) {
        s_part[a] = wsum[0] + wsum[1] + wsum[2] + wsum[3];
        np_part[a] = np;
    }
}

// ---------------- kernel 3: final reduction ------------------------------
__global__ __launch_bounds__(256) void k_reduce(const float* __restrict__ s_part,
                                                const int* __restrict__ np_part,
                                                float* __restrict__ out) {
    const int tid = threadIdx.x;
    double s = 0.0;
    long long c = 0;
    for (int i = tid; i < NN; i += 256) {
        s += (double)s_part[i];
        int np = np_part[i];
        c += (long long)np * (511 - np);
    }
#pragma unroll
    for (int off = 32; off > 0; off >>= 1) {
        s += __shfl_down(s, off);
        c += __shfl_down(c, off);
    }
    __shared__ double ws_[4];
    __shared__ long long wc_[4];
    if ((tid & 63) == 0) {
        ws_[tid >> 6] = s;
        wc_[tid >> 6] = c;
    }
    __syncthreads();
    if (tid == 0) {
        double tot = ws_[0] + ws_[1] + ws_[2] + ws_[3];
        long long cnt = wc_[0] + wc_[1] + wc_[2] + wc_[3];
        if (cnt < 1) cnt = 1;
        out[0] = (float)(tot / (double)cnt);
    }
}

extern "C" void kernel_launch(void* const* d_in, const int* in_sizes, int n_in,
                              void* d_out, int out_size, void* d_ws, size_t ws_size,
                              hipStream_t stream) {
    const float* E = (const float*)d_in[0];
    const int* labels = (const int*)d_in[1];
    float* out = (float*)d_out;

    // workspace layout (bytes)
    float* dist = (float*)d_ws;                                  // 1 MiB
    float* s_part = (float*)((char*)d_ws + (size_t)NN * NN * 4); // 2 KiB
    int* np_part = (int*)((char*)s_part + (size_t)NN * 4);       // 2 KiB

    k_dist<<<dim3(16, 16), 256, 0, stream>>>(E, dist);
    k_triplet<<<NN, 256, 0, stream>>>(dist, labels, s_part, np_part);
    k_reduce<<<1, 256, 0, stream>>>(s_part, np_part, out);
}

// Round 16
// 68.635 us; speedup vs baseline: 2.5227x; 1.0822x over previous
//
#include <hip/hip_runtime.h>
#include <hip/hip_bf16.h>

#define NN 512
#define DD 512
#define MARGIN_F 1.0f

constexpr int BM = 64, BN = 64, BK = 32, KSPLIT = 4, KCH = DD / KSPLIT;

// ---------------- kernel 1: partial grams part[z] = E_z E_z^T ------------
// Plain stores (no init needed, no atomics). Diagonal blocks also write
// diag[z][j] = part[z][j][j].
__global__ __launch_bounds__(256) void k_gram(const float* __restrict__ E,
                                              float* __restrict__ part,
                                              float* __restrict__ diag) {
    __shared__ float As[BK][BM + 4];  // k-major, +4 pad
    __shared__ float Bs[BK][BN + 4];
    const int tid = threadIdx.x;
    const int tx = tid & 15, ty = tid >> 4;
    const int row0 = blockIdx.y * BM, col0 = blockIdx.x * BN;
    const int z = blockIdx.z;
    const int k0 = z * KCH;
    float acc[4][4] = {};
    for (int kt = 0; kt < KCH; kt += BK) {
#pragma unroll
        for (int q = 0; q < 2; ++q) {
            int idx = tid + q * 256;  // 0..511
            int r = idx >> 3;         // 0..63
            int kv = idx & 7;         // float4 within the 32-wide K tile
            float4 va = *reinterpret_cast<const float4*>(
                &E[(size_t)(row0 + r) * DD + k0 + kt + kv * 4]);
            As[kv * 4 + 0][r] = va.x;
            As[kv * 4 + 1][r] = va.y;
            As[kv * 4 + 2][r] = va.z;
            As[kv * 4 + 3][r] = va.w;
            float4 vb = *reinterpret_cast<const float4*>(
                &E[(size_t)(col0 + r) * DD + k0 + kt + kv * 4]);
            Bs[kv * 4 + 0][r] = vb.x;
            Bs[kv * 4 + 1][r] = vb.y;
            Bs[kv * 4 + 2][r] = vb.z;
            Bs[kv * 4 + 3][r] = vb.w;
        }
        __syncthreads();
#pragma unroll
        for (int k = 0; k < BK; ++k) {
            float4 av = *reinterpret_cast<const float4*>(&As[k][ty * 4]);
            float4 bv = *reinterpret_cast<const float4*>(&Bs[k][tx * 4]);
            float a[4] = {av.x, av.y, av.z, av.w};
            float b[4] = {bv.x, bv.y, bv.z, bv.w};
#pragma unroll
            for (int i = 0; i < 4; ++i)
#pragma unroll
                for (int j = 0; j < 4; ++j) acc[i][j] += a[i] * b[j];
        }
        __syncthreads();
    }
    float* pz = part + (size_t)z * NN * NN;
#pragma unroll
    for (int i = 0; i < 4; ++i) {
        int gi = row0 + ty * 4 + i;
        float4 st = make_float4(acc[i][0], acc[i][1], acc[i][2], acc[i][3]);
        *reinterpret_cast<float4*>(&pz[(size_t)gi * NN + col0 + tx * 4]) = st;
    }
    if (row0 == col0 && tx == ty) {
#pragma unroll
        for (int i = 0; i < 4; ++i) diag[z * NN + row0 + ty * 4 + i] = acc[i][i];
    }
}

// ---------------- kernel 2: per-anchor triplet accumulation --------------
// dist(a,j) = g_aa + g_jj - 2*g_aj, reconstructed from the 4 partials.
// Writes per-anchor {sum, nPos} with plain stores (no global atomics).
__global__ __launch_bounds__(256) void k_triplet(const float* __restrict__ part,
                                                 const float* __restrict__ diag,
                                                 const int* __restrict__ labels,
                                                 float* __restrict__ s_part,
                                                 int* __restrict__ np_part) {
    const int a = blockIdx.x;
    const int tid = threadIdx.x;
    __shared__ float posv[NN];
    __shared__ int nPos;
    if (tid == 0) nPos = 0;
    __syncthreads();
    const int la = labels[a];
    const float g_aa = diag[0 * NN + a] + diag[1 * NN + a] + diag[2 * NN + a] + diag[3 * NN + a];
    float dval[2];
    int neg[2];
#pragma unroll
    for (int q = 0; q < 2; ++q) {
        int j = tid + q * 256;
        float g_aj = part[(size_t)0 * NN * NN + (size_t)a * NN + j] +
                     part[(size_t)1 * NN * NN + (size_t)a * NN + j] +
                     part[(size_t)2 * NN * NN + (size_t)a * NN + j] +
                     part[(size_t)3 * NN * NN + (size_t)a * NN + j];
        float g_jj = diag[j] + diag[NN + j] + diag[2 * NN + j] + diag[3 * NN + j];
        float d = g_aa + g_jj - 2.0f * g_aj;
        dval[q] = d;
        neg[q] = 0;
        if (j != a) {
            if (labels[j] == la) {
                int p = atomicAdd(&nPos, 1);  // LDS atomic, cheap
                posv[p] = d;
            } else {
                neg[q] = 1;
            }
        }
    }
    __syncthreads();
    const int np = nPos;  // block-uniform
    float acc = 0.f;
#pragma unroll
    for (int q = 0; q < 2; ++q) {
        if (neg[q]) {
            float b = MARGIN_F - dval[q];  // term = pos - dval + margin
            for (int p = 0; p < np; ++p) acc += fmaxf(posv[p] + b, 0.f);
        }
    }
#pragma unroll
    for (int off = 32; off > 0; off >>= 1) acc += __shfl_down(acc, off);
    __shared__ float wsum[4];
    if ((tid & 63) == 0) wsum[tid >> 6] = acc;
    __syncthreads();
    if (tid == 0) {
        s_part[a] = wsum[0] + wsum[1] + wsum[2] + wsum[3];
        np_part[a] = np;
    }
}

// ---------------- kernel 3: final reduction ------------------------------
__global__ __launch_bounds__(256) void k_reduce(const float* __restrict__ s_part,
                                                const int* __restrict__ np_part,
                                                float* __restrict__ out) {
    const int tid = threadIdx.x;
    double s = 0.0;
    long long c = 0;
    for (int i = tid; i < NN; i += 256) {
        s += (double)s_part[i];
        int np = np_part[i];
        c += (long long)np * (511 - np);
    }
#pragma unroll
    for (int off = 32; off > 0; off >>= 1) {
        s += __shfl_down(s, off);
        c += __shfl_down(c, off);
    }
    __shared__ double ws_[4];
    __shared__ long long wc_[4];
    if ((tid & 63) == 0) {
        ws_[tid >> 6] = s;
        wc_[tid >> 6] = c;
    }
    __syncthreads();
    if (tid == 0) {
        double tot = ws_[0] + ws_[1] + ws_[2] + ws_[3];
        long long cnt = wc_[0] + wc_[1] + wc_[2] + wc_[3];
        if (cnt < 1) cnt = 1;
        out[0] = (float)(tot / (double)cnt);
    }
}

extern "C" void kernel_launch(void* const* d_in, const int* in_sizes, int n_in,
                              void* d_out, int out_size, void* d_ws, size_t ws_size,
                              hipStream_t stream) {
    const float* E = (const float*)d_in[0];
    const int* labels = (const int*)d_in[1];
    float* out = (float*)d_out;

    // workspace layout (bytes)
    float* part = (float*)d_ws;                                          // 4 MiB
    float* diag = (float*)((char*)d_ws + (size_t)KSPLIT * NN * NN * 4);  // 8 KiB
    float* s_part = (float*)((char*)diag + (size_t)KSPLIT * NN * 4);     // 2 KiB
    int* np_part = (int*)((char*)s_part + (size_t)NN * 4);               // 2 KiB

    k_gram<<<dim3(NN / BN, NN / BM, KSPLIT), 256, 0, stream>>>(E, part, diag);
    k_triplet<<<NN, 256, 0, stream>>>(part, diag, labels, s_part, np_part);
    k_reduce<<<1, 256, 0, stream>>>(s_part, np_part, out);
}